// Round 8
// baseline (262.204 us; speedup 1.0000x reference)
//
#include <hip/hip_runtime.h>
#include <cstddef>
#include <cstdint>

#define NEG_SENT (-1.0e30f)

// =====================================================================
//  W=4096, H=2048, D=768, HID=1024, E=64, CC=64, K=3, SENT_LEN=32, MD=128
//  sent_id[w]=w>>5 -> packed cols s*32+p all valid; eid=off-p+63 in [32,94]
//
//  R8: k_fused processes 4 heads / 512 threads (halves the dominant
//  w2F L2 re-read term: 512->256 MB), K-chunk 128 staged coalesced
//  (4 thr/row, 1 kstep/thread). AWb combined bf16 (R5's best-FETCH
//  layout). k_mid = pure GEMM1; sort/small-cvt/embC folded into prep0.
// =====================================================================

typedef short s8v __attribute__((ext_vector_type(8)));
typedef float f32x4 __attribute__((ext_vector_type(4)));

static __device__ __forceinline__ f32x4 mfma16(s8v a, s8v b, f32x4 c) {
  return __builtin_amdgcn_mfma_f32_16x16x32_bf16(a, b, c, 0, 0, 0);
}
static __device__ __forceinline__ unsigned short f2b(float f) {
  union { float f; unsigned u; } v{f};
  unsigned r = v.u + 0x7FFF + ((v.u >> 16) & 1);
  return (unsigned short)(r >> 16);
}
static __device__ __forceinline__ float b2f(unsigned short u) {
  union { unsigned u; float f; } v{((unsigned)u) << 16};
  return v.f;
}
static __device__ __forceinline__ unsigned pk2(float a, float b) {
#if defined(__gfx950__) && __has_builtin(__builtin_amdgcn_cvt_pk_bf16_f32)
  typedef __bf16 b2t __attribute__((ext_vector_type(2)));
  b2t r = __builtin_amdgcn_cvt_pk_bf16_f32(a, b);
  return __builtin_bit_cast(unsigned, r);
#else
  return (unsigned)f2b(a) | ((unsigned)f2b(b) << 16);
#endif
}
static __device__ __forceinline__ float blo(unsigned u) {
  union { unsigned u; float f; } v{u << 16}; return v.f;
}
static __device__ __forceinline__ float bhi(unsigned u) {
  union { unsigned u; float f; } v{u & 0xffff0000u}; return v.f;
}

// ---------- prep0: w1F (0..767) | w2F (768..895) | w3F (896..903)
//            | c1F (904..909) | embC (910..1037) | sort (1038) ----------
__global__ __launch_bounds__(256) void k_prep0(
    const float* __restrict__ w1, const float* __restrict__ b1,
    const float* __restrict__ emb, const float* __restrict__ w2,
    const float* __restrict__ w3, const float* __restrict__ c1w,
    const int* __restrict__ heads, s8v* __restrict__ w1F,
    s8v* __restrict__ w2F, s8v* __restrict__ w3F, s8v* __restrict__ c1F,
    unsigned short* __restrict__ embCb, int* __restrict__ ord) {
  const int bx = blockIdx.x, t = threadIdx.x;
  __shared__ float se[64];
  __shared__ int hist[128], base_[128];
  if (bx < 768) {  // w1 -> B-frag (N=2048 combined; z=n>>10 picks half)
    const int tid = bx * 256 + t;
    const int lane = tid & 63, ks = (tid >> 6) % 24, nt = tid / 1536;
    const int n = nt * 16 + (lane & 15);
    const int kb = ks * 32 + 8 * (lane >> 4);
    const int z = n >> 10, col = n & 1023;
    const float* src = w1 + (size_t)(z * 768 + kb) * 1024 + col;
    s8v p;
#pragma unroll
    for (int j = 0; j < 8; ++j) p[j] = (short)f2b(src[(size_t)j * 1024]);
    w1F[tid] = p;
  } else if (bx < 896) {  // w2 [1024][256] -> [16 nt][32 ks][64][8]
    const int tid = (bx - 768) * 256 + t;
    const int lane = tid & 63, ks = (tid >> 6) % 32, nt = tid / 2048;
    const int n = nt * 16 + (lane & 15);
    const int kb = ks * 32 + 8 * (lane >> 4);
    s8v p;
#pragma unroll
    for (int j = 0; j < 8; ++j) p[j] = (short)f2b(w2[(size_t)(kb + j) * 256 + n]);
    w2F[tid] = p;
  } else if (bx < 904) {  // w3 [256][64] -> [4 nt][8 ks][64][8]
    const int tid = (bx - 896) * 256 + t;
    const int lane = tid & 63, ks = (tid >> 6) % 8, nt = tid / 512;
    const int n = nt * 16 + (lane & 15);
    const int kb = ks * 32 + 8 * (lane >> 4);
    s8v p;
#pragma unroll
    for (int j = 0; j < 8; ++j) p[j] = (short)f2b(w3[(size_t)(kb + j) * 64 + n]);
    w3F[tid] = p;
  } else if (bx < 910) {  // c1w [64][64][3] -> [4 nt][6 ks][64][8], k=tap*64+c
    const int tid = (bx - 904) * 256 + t;
    const int lane = tid & 63, ks = (tid >> 6) % 6, nt = tid / 384;
    const int o = nt * 16 + (lane & 15);
    const int kb = ks * 32 + 8 * (lane >> 4);
    s8v p;
#pragma unroll
    for (int j = 0; j < 8; ++j) {
      const int k = kb + j, tap = k >> 6, c = k & 63;
      p[j] = (short)f2b(c1w[(size_t)(o * 64 + c) * 3 + tap]);
    }
    c1F[tid] = p;
  } else if (bx < 1038) {  // embCb[e] = bf16(emb[e] @ w1[1536:1600,:] + b1)
    const int e = bx - 910;
    if (t < 64) se[t] = emb[e * 64 + t];
    __syncthreads();
    float4 acc = *reinterpret_cast<const float4*>(b1 + 4 * t);
#pragma unroll 8
    for (int d = 0; d < 64; ++d) {
      const float4 wv =
          *reinterpret_cast<const float4*>(w1 + (size_t)(1536 + d) * 1024 + 4 * t);
      const float a = se[d];
      acc.x += a * wv.x; acc.y += a * wv.y; acc.z += a * wv.z; acc.w += a * wv.w;
    }
    uint2 r; r.x = pk2(acc.x, acc.y); r.y = pk2(acc.z, acc.w);
    *reinterpret_cast<uint2*>(embCb + (size_t)e * 1024 + 4 * t) = r;
  } else {  // counting sort of head indices by sentence -> ord[2048]
    if (t < 128) hist[t] = 0;
    __syncthreads();
    for (int h = t; h < 2048; h += 256) atomicAdd(&hist[(heads[h] >> 5) & 127], 1);
    __syncthreads();
    if (t == 0) {
      int s = 0;
      for (int i = 0; i < 128; ++i) { base_[i] = s; s += hist[i]; }
    }
    __syncthreads();
    for (int h = t; h < 2048; h += 256) {
      const int s = (heads[h] >> 5) & 127;
      const int p = atomicAdd(&base_[s], 1);
      ord[p] = h;
    }
  }
}

// ---------- k_mid: GEMM1 -> AWb[4096][2048] bf16 (512 blocks) ----------
__global__ __launch_bounds__(256) void k_mid(const float* __restrict__ words,
                                             const s8v* __restrict__ w1F,
                                             unsigned short* __restrict__ AWb) {
  const int bx = blockIdx.x, t = threadIdx.x;
  __shared__ short As[2][8][2][64][8];   // [buf][mt][ks][lane][idx], 32 KB
  const int lane = t & 63, w = t >> 6;
  const int mq = w & 1, nq = w >> 1;
  const int m0 = (bx >> 4) * 128;
  const int nb = bx & 15;
  const int mA = t >> 1;
  const float* Ap = words + (size_t)(m0 + mA) * 768 + (t & 1) * 32;
  const s8v* Bp = w1F + (size_t)((nb * 8 + nq * 4) * 24) * 64 + lane;

  f32x4 acc[4][4] = {};
  float4 va[8];
  s8v bc[4][2], bn[4][2];

#pragma unroll
  for (int u = 0; u < 8; ++u) va[u] = *reinterpret_cast<const float4*>(Ap + 4 * u);
#pragma unroll
  for (int i = 0; i < 4; ++i)
#pragma unroll
    for (int ks = 0; ks < 2; ++ks) bc[i][ks] = Bp[(size_t)(i * 24 + ks) * 64];
#pragma unroll
  for (int g = 0; g < 4; ++g) {
    uint4 pu;
    pu.x = pk2(va[2 * g].x, va[2 * g].y);
    pu.y = pk2(va[2 * g].z, va[2 * g].w);
    pu.z = pk2(va[2 * g + 1].x, va[2 * g + 1].y);
    pu.w = pk2(va[2 * g + 1].z, va[2 * g + 1].w);
    *reinterpret_cast<uint4*>(&As[0][mA >> 4][t & 1][(mA & 15) + 16 * g][0]) = pu;
  }
  __syncthreads();

#pragma unroll
  for (int it = 0; it < 12; ++it) {
    const int buf = it & 1;
    if (it < 11) {
#pragma unroll
      for (int u = 0; u < 8; ++u)
        va[u] = *reinterpret_cast<const float4*>(Ap + (it + 1) * 64 + 4 * u);
#pragma unroll
      for (int i = 0; i < 4; ++i)
#pragma unroll
        for (int ks = 0; ks < 2; ++ks)
          bn[i][ks] = Bp[(size_t)(i * 24 + (it + 1) * 2 + ks) * 64];
    }
#pragma unroll
    for (int ks = 0; ks < 2; ++ks) {
      s8v a[4];
#pragma unroll
      for (int i = 0; i < 4; ++i)
        a[i] = *reinterpret_cast<const s8v*>(&As[buf][mq * 4 + i][ks][lane][0]);
#pragma unroll
      for (int i = 0; i < 4; ++i)
#pragma unroll
        for (int j = 0; j < 4; ++j)
          acc[i][j] = mfma16(a[i], bc[j][ks], acc[i][j]);
    }
    if (it < 11) {
#pragma unroll
      for (int g = 0; g < 4; ++g) {
        uint4 pu;
        pu.x = pk2(va[2 * g].x, va[2 * g].y);
        pu.y = pk2(va[2 * g].z, va[2 * g].w);
        pu.z = pk2(va[2 * g + 1].x, va[2 * g + 1].y);
        pu.w = pk2(va[2 * g + 1].z, va[2 * g + 1].w);
        *reinterpret_cast<uint4*>(
            &As[buf ^ 1][mA >> 4][t & 1][(mA & 15) + 16 * g][0]) = pu;
      }
#pragma unroll
      for (int i = 0; i < 4; ++i)
#pragma unroll
        for (int ks = 0; ks < 2; ++ks) bc[i][ks] = bn[i][ks];
    }
    __syncthreads();
  }

  const int rl = (lane >> 4) * 4, cl2 = lane & 15;
#pragma unroll
  for (int i = 0; i < 4; ++i)
#pragma unroll
    for (int j = 0; j < 4; ++j) {
      const int n = nq * 64 + j * 16 + cl2;   // 0..127 within n-block
#pragma unroll
      for (int r = 0; r < 4; ++r) {
        const int m = m0 + mq * 64 + i * 16 + rl + r;
        AWb[(size_t)m * 2048 + nb * 128 + n] = f2b(acc[i][j][r]);
      }
    }
}

// ---------- fused per-4-head block, 512 threads / 8 waves ----------
__global__ __launch_bounds__(512) void k_fused(
    const int* __restrict__ heads, const int* __restrict__ ord,
    const unsigned short* __restrict__ AWb,
    const unsigned short* __restrict__ embCb, const s8v* __restrict__ w2F,
    const float* __restrict__ b2, const s8v* __restrict__ w3F,
    const float* __restrict__ b3, const s8v* __restrict__ c1F,
    const float* __restrict__ c1b, const float* __restrict__ c2w,
    const float* __restrict__ c2b, float* __restrict__ out) {
  const int t = threadIdx.x, lane = t & 63, w = t >> 6;
  const int q = lane >> 4, cl = lane & 15;
  const int nq = w & 3, ph = w >> 2;

  const int4 hord = *reinterpret_cast<const int4*>(ord + 4 * blockIdx.x);
  const int ho[4] = {hord.x, hord.y, hord.z, hord.w};
  int hids[4];
#pragma unroll
  for (int r = 0; r < 4; ++r) hids[r] = heads[ho[r]];

  __shared__ unsigned short sHead[4][1024];        // 8 KB
  __shared__ __align__(16) char rgn[67584];        // staging dbuf / tail alias
  s8v* sB1 = reinterpret_cast<s8v*>(rgn);          // ((buf*8+ntp)*4+k2)*66+slot
  unsigned short* sX2u = reinterpret_cast<unsigned short*>(rgn);
  s8v* sFr = reinterpret_cast<s8v*>(rgn);          // generic frag view
  unsigned short* sY1b = reinterpret_cast<unsigned short*>(rgn + 49152);

  // sentinel fill of all 4 heads' output rows
  {
    float4 m4; m4.x = m4.y = m4.z = m4.w = NEG_SENT;
#pragma unroll
    for (int r = 0; r < 4; ++r) {
      float4* orow = reinterpret_cast<float4*>(out + (size_t)ho[r] * 8192);
      const int sr = hids[r] >> 5;
#pragma unroll
      for (int i = 0; i < 4; ++i) {
        const int fi = t + (i << 9);
        if ((fi >> 4) != sr) orow[fi] = m4;
      }
    }
  }

  // head rows: AWb[hid][0:1024] bf16 -> LDS (t -> head t>>7, seg t&127)
  {
    const int hd = t >> 7, seg = t & 127;
    *reinterpret_cast<uint4*>(&sHead[hd][seg * 8]) =
        *reinterpret_cast<const uint4*>(AWb + (size_t)hids[hd] * 2048 + seg * 8);
  }

  // staging coords: row = t>>2 (of 128), kstep-in-chunk k2 = t&3 (32 k each)
  const int srow = t >> 2, k2 = t & 3;
  const int shd = srow >> 5, spos = srow & 31;
  const int hidS = hids[shd];
  const size_t woff = (size_t)((hidS >> 5) * 32 + spos) * 2048 + 1024 + k2 * 32;
  const size_t eoff = (size_t)((hidS & 31) - spos + 63) * 1024 + k2 * 32;
  const unsigned short* hptr = &sHead[shd][k2 * 32];
  const int sntp = srow >> 4, sl0 = srow & 15;
  const size_t wrBase = (size_t)((sntp * 4 + k2) * 66) + sl0;  // + buf*2112 + 16g

  uint4 pw[4], pe[4];
#pragma unroll
  for (int g = 0; g < 4; ++g) {
    pw[g] = *reinterpret_cast<const uint4*>(AWb + woff + 8 * g);
    pe[g] = *reinterpret_cast<const uint4*>(embCb + eoff + 8 * g);
  }
  __syncthreads();  // sHead visible

  auto stage = [&](int buf, int coff) {
#pragma unroll
    for (int g = 0; g < 4; ++g) {
      const uint4 hv = *reinterpret_cast<const uint4*>(hptr + coff + 8 * g);
      uint4 o;
      o.x = pk2(fmaxf(blo(pw[g].x) + blo(pe[g].x) + blo(hv.x), 0.f),
                fmaxf(bhi(pw[g].x) + bhi(pe[g].x) + bhi(hv.x), 0.f));
      o.y = pk2(fmaxf(blo(pw[g].y) + blo(pe[g].y) + blo(hv.y), 0.f),
                fmaxf(bhi(pw[g].y) + bhi(pe[g].y) + bhi(hv.y), 0.f));
      o.z = pk2(fmaxf(blo(pw[g].z) + blo(pe[g].z) + blo(hv.z), 0.f),
                fmaxf(bhi(pw[g].z) + bhi(pe[g].z) + bhi(hv.z), 0.f));
      o.w = pk2(fmaxf(blo(pw[g].w) + blo(pe[g].w) + blo(hv.w), 0.f),
                fmaxf(bhi(pw[g].w) + bhi(pe[g].w) + bhi(hv.w), 0.f));
      *reinterpret_cast<uint4*>(&sB1[wrBase + (size_t)buf * 2112 + 16 * g]) = o;
    }
  };

  f32x4 acc[4][4] = {};  // [i: n2-tile nq*4+i][j: ntp ph*4+j]
  const s8v* avp = w2F + (size_t)(nq * 4) * 32 * 64 + lane;
  const size_t rdBase = (size_t)(ph * 4) * 4 * 66 + lane;

  stage(0, 0);
  __syncthreads();

#pragma unroll
  for (int jc = 0; jc < 8; ++jc) {
    const int buf = jc & 1;
    if (jc < 7) {
      const int j1 = (jc + 1) * 128;
#pragma unroll
      for (int g = 0; g < 4; ++g) {
        pw[g] = *reinterpret_cast<const uint4*>(AWb + woff + j1 + 8 * g);
        pe[g] = *reinterpret_cast<const uint4*>(embCb + eoff + j1 + 8 * g);
      }
    }
#pragma unroll
    for (int k2i = 0; k2i < 4; ++k2i) {
      s8v av[4], bv[4];
#pragma unroll
      for (int i = 0; i < 4; ++i)
        av[i] = avp[(size_t)(i * 32 + jc * 4 + k2i) * 64];
#pragma unroll
      for (int j = 0; j < 4; ++j)
        bv[j] = sB1[rdBase + (size_t)buf * 2112 + (size_t)(j * 4 + k2i) * 66];
#pragma unroll
      for (int i = 0; i < 4; ++i)
#pragma unroll
        for (int j = 0; j < 4; ++j)
          acc[i][j] = mfma16(av[i], bv[j], acc[i][j]);
    }
    if (jc < 7) stage(buf ^ 1, (jc + 1) * 128);
    __syncthreads();
  }

  // GEMM2' epilogue: X2^T = relu(acc+b2) -> B-frags [ntp(8)][ks3(8)][64][8]
#pragma unroll
  for (int i = 0; i < 4; ++i) {
    const int n2b = (nq * 4 + i) * 16 + q * 4;
    const float4 bb = *reinterpret_cast<const float4*>(b2 + n2b);
    const int ks3 = n2b >> 5, g3 = (n2b >> 3) & 3, idx0 = n2b & 7;
#pragma unroll
    for (int j = 0; j < 4; ++j) {
      const int ntp = ph * 4 + j;
      const unsigned u0 = pk2(fmaxf(acc[i][j][0] + bb.x, 0.f),
                              fmaxf(acc[i][j][1] + bb.y, 0.f));
      const unsigned u1 = pk2(fmaxf(acc[i][j][2] + bb.z, 0.f),
                              fmaxf(acc[i][j][3] + bb.w, 0.f));
      uint2 uu; uu.x = u0; uu.y = u1;
      *reinterpret_cast<uint2*>(
          sX2u + (((size_t)ntp * 8 + ks3) * 64 + cl + 16 * g3) * 8 + idx0) = uu;
    }
  }
  __syncthreads();

  // GEMM3': X3^T[c][p']; wave -> c-tile nq, ntp = ph*4+j
  f32x4 acc3[4] = {};
#pragma unroll
  for (int ks3 = 0; ks3 < 8; ++ks3) {
    const s8v a = w3F[(size_t)(nq * 8 + ks3) * 64 + lane];
#pragma unroll
    for (int j = 0; j < 4; ++j)
      acc3[j] = mfma16(a, sFr[(size_t)((ph * 4 + j) * 8 + ks3) * 64 + lane], acc3[j]);
  }
  __syncthreads();  // X2f consumed; conv frag region may be overwritten

  // conv1' im2col frag writes [ntp(8)][ks(6)][64][8] + zero pads + Y1 pads
  {
    const int cb = nq * 16 + q * 4;
    const float4 b3v = *reinterpret_cast<const float4*>(b3 + cb);
    const int gC = (cb >> 3) & 3, idx0 = cb & 7, ksb = cb >> 5;  // ksb = nq>>1
#pragma unroll
    for (int j = 0; j < 4; ++j) {
      const int pp = (ph * 4 + j) * 16 + cl, hd = pp >> 5, pos = pp & 31;
      const unsigned u0 = pk2(acc3[j][0] + b3v.x, acc3[j][1] + b3v.y);
      const unsigned u1 = pk2(acc3[j][2] + b3v.z, acc3[j][3] + b3v.w);
      uint2 uu; uu.x = u0; uu.y = u1;
#pragma unroll
      for (int tau = 0; tau < 3; ++tau) {
        const int pt = pos + 1 - tau;
        if ((unsigned)pt < 32u) {
          const int ppt = hd * 32 + pt;
          const int ks = 2 * tau + ksb;
          *reinterpret_cast<uint2*>(
              sX2u + (((size_t)(ppt >> 4) * 6 + ks) * 64 + (ppt & 15) + 16 * gC) * 8 +
              idx0) = uu;
        }
      }
    }
    if (t < 64) {  // conv pad slots: (tau=0,pos=0) and (tau=2,pos=31) per head
      const int hd = t >> 4, grp = (t >> 3) & 1;
      const int ksz = (grp ? 4 : 0) + ((t >> 2) & 1), kg = t & 3;
      const int ntpz = 2 * hd + grp, lnz = (grp ? 15 : 0) + 16 * kg;
      uint4 z; z.x = z.y = z.z = z.w = 0;
      *reinterpret_cast<uint4*>(
          &sFr[(size_t)(ntpz * 6 + ksz) * 64 + lnz]) = z;
    }
    // Y1 zero pad cols (0,33) per head block of 34
    const int oY = t >> 3, pc = t & 7;
    sY1b[oY * 136 + (pc >> 1) * 34 + ((pc & 1) ? 33 : 0)] = 0;
  }
  __syncthreads();

  // conv1' MFMA: Y1^T[o][p']; wave -> o-tile nq, ntp = ph*4+j
  f32x4 accc[4] = {};
#pragma unroll
  for (int ks = 0; ks < 6; ++ks) {
    const s8v a = c1F[(size_t)(nq * 6 + ks) * 64 + lane];
#pragma unroll
    for (int j = 0; j < 4; ++j)
      accc[j] = mfma16(a, sFr[(size_t)((ph * 4 + j) * 6 + ks) * 64 + lane], accc[j]);
  }
  {
    const int ob = nq * 16 + q * 4;
    const float4 cbv = *reinterpret_cast<const float4*>(c1b + ob);
#pragma unroll
    for (int j = 0; j < 4; ++j) {
      const int pp = (ph * 4 + j) * 16 + cl, hd = pp >> 5, pos = pp & 31;
      const int col = hd * 34 + 1 + pos;
      sY1b[(ob + 0) * 136 + col] = f2b(accc[j][0] + cbv.x);
      sY1b[(ob + 1) * 136 + col] = f2b(accc[j][1] + cbv.y);
      sY1b[(ob + 2) * 136 + col] = f2b(accc[j][2] + cbv.z);
      sY1b[(ob + 3) * 136 + col] = f2b(accc[j][3] + cbv.w);
    }
  }
  __syncthreads();

  // conv2 (64ch*3tap -> 2) on VALU, K split 2 ways + shuffle reduce, scatter
  {
    const int kq = t & 1, c2 = (t >> 1) & 1, pp = t >> 2;  // pp 0..127
    const int hd = pp >> 5, pos = pp & 31, col = hd * 34 + 1 + pos;
    float a2 = 0.f;
    const float* wp = c2w + (size_t)(c2 * 64 + kq * 32) * 3;
    const unsigned short* yb = sY1b + (size_t)(kq * 32) * 136 + col;
#pragma unroll
    for (int o = 0; o < 32; ++o) {
      a2 += b2f(yb[o * 136 - 1]) * wp[o * 3 + 0] +
            b2f(yb[o * 136]) * wp[o * 3 + 1] +
            b2f(yb[o * 136 + 1]) * wp[o * 3 + 2];
    }
    a2 += __shfl_xor(a2, 1, 64);
    if (kq == 0) {
      const int hidR = hids[hd];
      const int sR = hidR >> 5, offR = hidR & 31;
      const int rel = offR - pos;
      const bool ok = (c2 == 0) ? (rel >= 0) : (rel <= 0);
      out[(size_t)ho[hd] * 8192 + (size_t)(sR * 32 + pos) * 2 + c2] =
          ok ? (a2 + c2b[c2]) : NEG_SENT;
    }
  }
}

extern "C" void kernel_launch(void* const* d_in, const int* in_sizes, int n_in,
                              void* d_out, int out_size, void* d_ws,
                              size_t ws_size, hipStream_t stream) {
  const float* words = (const float*)d_in[1];
  const int* heads = (const int*)d_in[2];
  const float* emb = (const float*)d_in[3];
  const float* w1 = (const float*)d_in[4];
  const float* b1 = (const float*)d_in[5];
  const float* w2 = (const float*)d_in[6];
  const float* b2 = (const float*)d_in[7];
  const float* w3 = (const float*)d_in[8];
  const float* b3 = (const float*)d_in[9];
  const float* c1w = (const float*)d_in[10];
  const float* c1b = (const float*)d_in[11];
  const float* c2w = (const float*)d_in[12];
  const float* c2b = (const float*)d_in[13];
  float* out = (float*)d_out;

  char* ws = (char*)d_ws;
  unsigned short* embCb = (unsigned short*)ws;      ws += 128 * 1024 * 2;
  unsigned short* AWb = (unsigned short*)ws;        ws += 4096 * 2048 * 2;
  s8v* w1F = (s8v*)ws;                              ws += 196608 * 16;
  s8v* w2F = (s8v*)ws;                              ws += 32768 * 16;
  s8v* w3F = (s8v*)ws;                              ws += 2048 * 16;
  s8v* c1F = (s8v*)ws;                              ws += 1536 * 16;
  int* ord = (int*)ws;                              ws += 2048 * 4;

  k_prep0<<<1039, 256, 0, stream>>>(w1, b1, emb, w2, w3, c1w, heads, w1F, w2F,
                                    w3F, c1F, embCb, ord);
  k_mid<<<512, 256, 0, stream>>>(words, w1F, AWb);
  k_fused<<<512, 512, 0, stream>>>(heads, ord, AWb, embCb, w2F, b2, w3F, b3,
                                   c1F, c1b, c2w, c2b, out);
}

// Round 9
// 248.767 us; speedup vs baseline: 1.0540x; 1.0540x over previous
//
#include <hip/hip_runtime.h>
#include <cstddef>
#include <cstdint>

#define NEG_SENT (-1.0e30f)

// =====================================================================
//  W=4096, H=2048, D=768, HID=1024, E=64, CC=64, K=3, SENT_LEN=32, MD=128
//  sent_id[w]=w>>5 -> packed cols s*32+p all valid; eid=off-p+63 in [32,94]
//
//  R9: BARRIER-FREE GEMM2 K-loop. Each wave computes its B-fragments
//  (x1 = relu(AWword + embC + AWhead)) directly in registers from
//  gather loads (16 rows x 64B, fully-consumed lines) -- no staging LDS,
//  no K-loop __syncthreads. Wave tile: 8 n2-tiles x 2 p'-tiles.
//  words pre-converted to bf16 (halves k_mid A-traffic, staging is
//  pass-through ds_write_b128). Tail phases = R7's validated code.
// =====================================================================

typedef short s8v __attribute__((ext_vector_type(8)));
typedef float f32x4 __attribute__((ext_vector_type(4)));

static __device__ __forceinline__ f32x4 mfma16(s8v a, s8v b, f32x4 c) {
  return __builtin_amdgcn_mfma_f32_16x16x32_bf16(a, b, c, 0, 0, 0);
}
static __device__ __forceinline__ unsigned short f2b(float f) {
  union { float f; unsigned u; } v{f};
  unsigned r = v.u + 0x7FFF + ((v.u >> 16) & 1);
  return (unsigned short)(r >> 16);
}
static __device__ __forceinline__ float b2f(unsigned short u) {
  union { unsigned u; float f; } v{((unsigned)u) << 16};
  return v.f;
}
static __device__ __forceinline__ unsigned pk2(float a, float b) {
#if defined(__gfx950__) && __has_builtin(__builtin_amdgcn_cvt_pk_bf16_f32)
  typedef __bf16 b2t __attribute__((ext_vector_type(2)));
  b2t r = __builtin_amdgcn_cvt_pk_bf16_f32(a, b);
  return __builtin_bit_cast(unsigned, r);
#else
  return (unsigned)f2b(a) | ((unsigned)f2b(b) << 16);
#endif
}
static __device__ __forceinline__ float blo(unsigned u) {
  union { unsigned u; float f; } v{u << 16}; return v.f;
}
static __device__ __forceinline__ float bhi(unsigned u) {
  union { unsigned u; float f; } v{u & 0xffff0000u}; return v.f;
}

// ---------- prep0: wordsB (0..1535) | w1F (1536..2303) | w2F (2304..2431)
//   | w3F (2432..2439) | c1F (2440..2445) | embC (2446..2573) | sort (2574)
__global__ __launch_bounds__(256) void k_prep0(
    const float* __restrict__ words, const float* __restrict__ w1,
    const float* __restrict__ b1, const float* __restrict__ emb,
    const float* __restrict__ w2, const float* __restrict__ w3,
    const float* __restrict__ c1w, const int* __restrict__ heads,
    unsigned short* __restrict__ wordsB, s8v* __restrict__ w1F,
    s8v* __restrict__ w2F, s8v* __restrict__ w3F, s8v* __restrict__ c1F,
    unsigned short* __restrict__ embCb, int* __restrict__ ord) {
  const int bx = blockIdx.x, t = threadIdx.x;
  __shared__ float se[64];
  __shared__ int hist[128], base_[128];
  if (bx < 1536) {  // words fp32 -> bf16 row-major, 8 values/thread
    const size_t o = (size_t)(bx * 256 + t) * 8;
    const float4 v0 = *reinterpret_cast<const float4*>(words + o);
    const float4 v1 = *reinterpret_cast<const float4*>(words + o + 4);
    uint4 r;
    r.x = pk2(v0.x, v0.y); r.y = pk2(v0.z, v0.w);
    r.z = pk2(v1.x, v1.y); r.w = pk2(v1.z, v1.w);
    *reinterpret_cast<uint4*>(wordsB + o) = r;
  } else if (bx < 2304) {  // w1 -> B-frag (N=2048 combined)
    const int tid = (bx - 1536) * 256 + t;
    const int lane = tid & 63, ks = (tid >> 6) % 24, nt = tid / 1536;
    const int n = nt * 16 + (lane & 15);
    const int kb = ks * 32 + 8 * (lane >> 4);
    const int z = n >> 10, col = n & 1023;
    const float* src = w1 + (size_t)(z * 768 + kb) * 1024 + col;
    s8v p;
#pragma unroll
    for (int j = 0; j < 8; ++j) p[j] = (short)f2b(src[(size_t)j * 1024]);
    w1F[tid] = p;
  } else if (bx < 2432) {  // w2 [1024][256] -> [16 nt][32 ks][64][8]
    const int tid = (bx - 2304) * 256 + t;
    const int lane = tid & 63, ks = (tid >> 6) % 32, nt = tid / 2048;
    const int n = nt * 16 + (lane & 15);
    const int kb = ks * 32 + 8 * (lane >> 4);
    s8v p;
#pragma unroll
    for (int j = 0; j < 8; ++j) p[j] = (short)f2b(w2[(size_t)(kb + j) * 256 + n]);
    w2F[tid] = p;
  } else if (bx < 2440) {  // w3 [256][64] -> [4 nt][8 ks][64][8]
    const int tid = (bx - 2432) * 256 + t;
    const int lane = tid & 63, ks = (tid >> 6) % 8, nt = tid / 512;
    const int n = nt * 16 + (lane & 15);
    const int kb = ks * 32 + 8 * (lane >> 4);
    s8v p;
#pragma unroll
    for (int j = 0; j < 8; ++j) p[j] = (short)f2b(w3[(size_t)(kb + j) * 64 + n]);
    w3F[tid] = p;
  } else if (bx < 2446) {  // c1w [64][64][3] -> [4 nt][6 ks][64][8], k=tap*64+c
    const int tid = (bx - 2440) * 256 + t;
    const int lane = tid & 63, ks = (tid >> 6) % 6, nt = tid / 384;
    const int o = nt * 16 + (lane & 15);
    const int kb = ks * 32 + 8 * (lane >> 4);
    s8v p;
#pragma unroll
    for (int j = 0; j < 8; ++j) {
      const int k = kb + j, tap = k >> 6, c = k & 63;
      p[j] = (short)f2b(c1w[(size_t)(o * 64 + c) * 3 + tap]);
    }
    c1F[tid] = p;
  } else if (bx < 2574) {  // embCb[e] = bf16(emb[e] @ w1[1536:1600,:] + b1)
    const int e = bx - 2446;
    if (t < 64) se[t] = emb[e * 64 + t];
    __syncthreads();
    float4 acc = *reinterpret_cast<const float4*>(b1 + 4 * t);
#pragma unroll 8
    for (int d = 0; d < 64; ++d) {
      const float4 wv =
          *reinterpret_cast<const float4*>(w1 + (size_t)(1536 + d) * 1024 + 4 * t);
      const float a = se[d];
      acc.x += a * wv.x; acc.y += a * wv.y; acc.z += a * wv.z; acc.w += a * wv.w;
    }
    uint2 r; r.x = pk2(acc.x, acc.y); r.y = pk2(acc.z, acc.w);
    *reinterpret_cast<uint2*>(embCb + (size_t)e * 1024 + 4 * t) = r;
  } else {  // counting sort of head indices by sentence -> ord[2048]
    if (t < 128) hist[t] = 0;
    __syncthreads();
    for (int h = t; h < 2048; h += 256) atomicAdd(&hist[(heads[h] >> 5) & 127], 1);
    __syncthreads();
    if (t == 0) {
      int s = 0;
      for (int i = 0; i < 128; ++i) { base_[i] = s; s += hist[i]; }
    }
    __syncthreads();
    for (int h = t; h < 2048; h += 256) {
      const int s = (heads[h] >> 5) & 127;
      const int p = atomicAdd(&base_[s], 1);
      ord[p] = h;
    }
  }
}

// ---------- k_mid: GEMM1 -> AWb[4096][2048] bf16 (512 blocks, bf16 A) ------
__global__ __launch_bounds__(256) void k_mid(
    const unsigned short* __restrict__ wordsB, const s8v* __restrict__ w1F,
    unsigned short* __restrict__ AWb) {
  const int bx = blockIdx.x, t = threadIdx.x;
  __shared__ short As[2][8][2][64][8];   // [buf][mt][ks][lane][idx], 32 KB
  const int lane = t & 63, w = t >> 6;
  const int mq = w & 1, nq = w >> 1;
  const int m0 = (bx >> 4) * 128;
  const int nb = bx & 15;
  const int mA = t >> 1;
  const unsigned short* Ap = wordsB + (size_t)(m0 + mA) * 768 + (t & 1) * 32;
  const s8v* Bp = w1F + (size_t)((nb * 8 + nq * 4) * 24) * 64 + lane;

  f32x4 acc[4][4] = {};
  uint4 va[4];
  s8v bc[4][2], bn[4][2];

#pragma unroll
  for (int u = 0; u < 4; ++u) va[u] = *reinterpret_cast<const uint4*>(Ap + 8 * u);
#pragma unroll
  for (int i = 0; i < 4; ++i)
#pragma unroll
    for (int ks = 0; ks < 2; ++ks) bc[i][ks] = Bp[(size_t)(i * 24 + ks) * 64];
#pragma unroll
  for (int u = 0; u < 4; ++u)
    *reinterpret_cast<uint4*>(&As[0][mA >> 4][t & 1][(mA & 15) + 16 * u][0]) = va[u];
  __syncthreads();

#pragma unroll
  for (int it = 0; it < 12; ++it) {
    const int buf = it & 1;
    if (it < 11) {
#pragma unroll
      for (int u = 0; u < 4; ++u)
        va[u] = *reinterpret_cast<const uint4*>(Ap + (it + 1) * 64 + 8 * u);
#pragma unroll
      for (int i = 0; i < 4; ++i)
#pragma unroll
        for (int ks = 0; ks < 2; ++ks)
          bn[i][ks] = Bp[(size_t)(i * 24 + (it + 1) * 2 + ks) * 64];
    }
#pragma unroll
    for (int ks = 0; ks < 2; ++ks) {
      s8v a[4];
#pragma unroll
      for (int i = 0; i < 4; ++i)
        a[i] = *reinterpret_cast<const s8v*>(&As[buf][mq * 4 + i][ks][lane][0]);
#pragma unroll
      for (int i = 0; i < 4; ++i)
#pragma unroll
        for (int j = 0; j < 4; ++j)
          acc[i][j] = mfma16(a[i], bc[j][ks], acc[i][j]);
    }
    if (it < 11) {
#pragma unroll
      for (int u = 0; u < 4; ++u)
        *reinterpret_cast<uint4*>(
            &As[buf ^ 1][mA >> 4][t & 1][(mA & 15) + 16 * u][0]) = va[u];
#pragma unroll
      for (int i = 0; i < 4; ++i)
#pragma unroll
        for (int ks = 0; ks < 2; ++ks) bc[i][ks] = bn[i][ks];
    }
    __syncthreads();
  }

  const int rl = (lane >> 4) * 4, cl2 = lane & 15;
#pragma unroll
  for (int i = 0; i < 4; ++i)
#pragma unroll
    for (int j = 0; j < 4; ++j) {
      const int n = nq * 64 + j * 16 + cl2;
#pragma unroll
      for (int r = 0; r < 4; ++r) {
        const int m = m0 + mq * 64 + i * 16 + rl + r;
        AWb[(size_t)m * 2048 + nb * 128 + n] = f2b(acc[i][j][r]);
      }
    }
}

// ---------- fused per-2-head block, barrier-free GEMM2 K-loop ----------
__global__ __launch_bounds__(256) void k_fused(
    const int* __restrict__ heads, const int* __restrict__ ord,
    const unsigned short* __restrict__ AWb,
    const unsigned short* __restrict__ embCb, const s8v* __restrict__ w2F,
    const float* __restrict__ b2, const s8v* __restrict__ w3F,
    const float* __restrict__ b3, const s8v* __restrict__ c1F,
    const float* __restrict__ c1b, const float* __restrict__ c2w,
    const float* __restrict__ c2b, float* __restrict__ out) {
  const int t = threadIdx.x, lane = t & 63, w = t >> 6;
  const int q = lane >> 4, cl = lane & 15;
  const int ph = w >> 1, nh = w & 1;
  const int hA_ = ord[blockIdx.x * 2], hB_ = ord[blockIdx.x * 2 + 1];
  const int hidA = heads[hA_], hidB = heads[hB_];
  const int sA_ = hidA >> 5, sB_ = hidB >> 5;

  __shared__ unsigned short sHead[2][1024];     // bf16, 4 KB
  __shared__ __align__(16) char rgn[36864];     // X2 frags / conv frags / Y1
  unsigned short* sX2u = reinterpret_cast<unsigned short*>(rgn);
  s8v* sFr = reinterpret_cast<s8v*>(rgn);
  unsigned short* sY1b = reinterpret_cast<unsigned short*>(rgn + 24576);

  // sentinel fill of both heads' output rows
  {
    float4 m4; m4.x = m4.y = m4.z = m4.w = NEG_SENT;
    float4* o0 = reinterpret_cast<float4*>(out + (size_t)hA_ * 8192);
    float4* o1 = reinterpret_cast<float4*>(out + (size_t)hB_ * 8192);
#pragma unroll
    for (int i = 0; i < 8; ++i) {
      const int fi = t + (i << 8);
      if ((fi >> 4) != sA_) o0[fi] = m4;
      if ((fi >> 4) != sB_) o1[fi] = m4;
    }
  }

  // head rows: AWb[hid][0:1024] -> sHead
  {
    const uint2 ha = *reinterpret_cast<const uint2*>(AWb + (size_t)hidA * 2048 + 4 * t);
    const uint2 hb = *reinterpret_cast<const uint2*>(AWb + (size_t)hidB * 2048 + 4 * t);
    *reinterpret_cast<uint2*>(&sHead[0][4 * t]) = ha;
    *reinterpret_cast<uint2*>(&sHead[1][4 * t]) = hb;
  }
  __syncthreads();  // barrier #1 (the only one before the tail)

  // ---- barrier-free GEMM2' K-loop ----
  // wave: ph = head (p'-tiles ph*2+j, j=0,1), nh = n2-half (tiles nh*8+i)
  // B-frag for (j, ks): lane holds x1[p'][k0..k0+7], p' = (ph*2+j)*16+cl,
  //   k0 = ks*32 + 8q.  pos = j*16+cl (hd == ph uniform per wave).
  const int hidP = ph ? hidB : hidA;
  const int offP = hidP & 31;
  const unsigned short* wp0 =
      AWb + (size_t)((hidP >> 5) * 32 + cl) * 2048 + 1024 + 8 * q;
  const unsigned short* wp1 = wp0 + 16 * 2048;
  const unsigned short* ep0 = embCb + (size_t)(offP - cl + 63) * 1024 + 8 * q;
  const unsigned short* ep1 = ep0 - (size_t)16 * 1024;
  const unsigned short* hp = &sHead[ph][8 * q];
  const s8v* w2p = w2F + (size_t)(nh * 8) * 32 * 64 + lane;

  f32x4 acc[8][2] = {};
  uint4 cw0 = *reinterpret_cast<const uint4*>(wp0);
  uint4 cw1 = *reinterpret_cast<const uint4*>(wp1);
  uint4 ce0 = *reinterpret_cast<const uint4*>(ep0);
  uint4 ce1 = *reinterpret_cast<const uint4*>(ep1);
  uint4 chv = *reinterpret_cast<const uint4*>(hp);

#pragma unroll 4
  for (int ks = 0; ks < 32; ++ks) {
    uint4 b0u, b1u;
    b0u.x = pk2(fmaxf(blo(cw0.x) + blo(ce0.x) + blo(chv.x), 0.f),
                fmaxf(bhi(cw0.x) + bhi(ce0.x) + bhi(chv.x), 0.f));
    b0u.y = pk2(fmaxf(blo(cw0.y) + blo(ce0.y) + blo(chv.y), 0.f),
                fmaxf(bhi(cw0.y) + bhi(ce0.y) + bhi(chv.y), 0.f));
    b0u.z = pk2(fmaxf(blo(cw0.z) + blo(ce0.z) + blo(chv.z), 0.f),
                fmaxf(bhi(cw0.z) + bhi(ce0.z) + bhi(chv.z), 0.f));
    b0u.w = pk2(fmaxf(blo(cw0.w) + blo(ce0.w) + blo(chv.w), 0.f),
                fmaxf(bhi(cw0.w) + bhi(ce0.w) + bhi(chv.w), 0.f));
    b1u.x = pk2(fmaxf(blo(cw1.x) + blo(ce1.x) + blo(chv.x), 0.f),
                fmaxf(bhi(cw1.x) + bhi(ce1.x) + bhi(chv.x), 0.f));
    b1u.y = pk2(fmaxf(blo(cw1.y) + blo(ce1.y) + blo(chv.y), 0.f),
                fmaxf(bhi(cw1.y) + bhi(ce1.y) + bhi(chv.y), 0.f));
    b1u.z = pk2(fmaxf(blo(cw1.z) + blo(ce1.z) + blo(chv.z), 0.f),
                fmaxf(bhi(cw1.z) + bhi(ce1.z) + bhi(chv.z), 0.f));
    b1u.w = pk2(fmaxf(blo(cw1.w) + blo(ce1.w) + blo(chv.w), 0.f),
                fmaxf(bhi(cw1.w) + bhi(ce1.w) + bhi(chv.w), 0.f));
    const s8v bv0 = __builtin_bit_cast(s8v, b0u);
    const s8v bv1 = __builtin_bit_cast(s8v, b1u);
    if (ks < 31) {  // prefetch next kstep (overwrites cur after consumption)
      cw0 = *reinterpret_cast<const uint4*>(wp0 + 32 * (ks + 1));
      cw1 = *reinterpret_cast<const uint4*>(wp1 + 32 * (ks + 1));
      ce0 = *reinterpret_cast<const uint4*>(ep0 + 32 * (ks + 1));
      ce1 = *reinterpret_cast<const uint4*>(ep1 + 32 * (ks + 1));
      chv = *reinterpret_cast<const uint4*>(hp + 32 * (ks + 1));
    }
#pragma unroll
    for (int i = 0; i < 8; ++i) {
      const s8v av = w2p[(size_t)(i * 32 + ks) * 64];
      acc[i][0] = mfma16(av, bv0, acc[i][0]);
      acc[i][1] = mfma16(av, bv1, acc[i][1]);
    }
  }

  // GEMM2' epilogue: X2^T = relu(acc+b2) -> B-frags [ntp(4)][ks3(8)][64][8]
#pragma unroll
  for (int i = 0; i < 8; ++i) {
    const int n2b = (nh * 8 + i) * 16 + q * 4;
    const float4 bb = *reinterpret_cast<const float4*>(b2 + n2b);
    const int ks3 = n2b >> 5, g3 = (n2b >> 3) & 3, idx0 = n2b & 7;
#pragma unroll
    for (int j = 0; j < 2; ++j) {
      const int ntp = ph * 2 + j;
      const unsigned u0 = pk2(fmaxf(acc[i][j][0] + bb.x, 0.f),
                              fmaxf(acc[i][j][1] + bb.y, 0.f));
      const unsigned u1 = pk2(fmaxf(acc[i][j][2] + bb.z, 0.f),
                              fmaxf(acc[i][j][3] + bb.w, 0.f));
      uint2 uu; uu.x = u0; uu.y = u1;
      *reinterpret_cast<uint2*>(
          sX2u + (((size_t)ntp * 8 + ks3) * 64 + cl + 16 * g3) * 8 + idx0) = uu;
    }
  }
  __syncthreads();

  // GEMM3': X3^T[c][p']; wave w -> c-tile w
  f32x4 acc3[4] = {};
#pragma unroll
  for (int ks3 = 0; ks3 < 8; ++ks3) {
    const s8v a = w3F[(size_t)(w * 8 + ks3) * 64 + lane];
#pragma unroll
    for (int ntp = 0; ntp < 4; ++ntp)
      acc3[ntp] = mfma16(a, sFr[(size_t)(ntp * 8 + ks3) * 64 + lane], acc3[ntp]);
  }
  __syncthreads();  // X2 frags consumed; conv frag region may be overwritten

  // conv1' im2col frag writes [ntp(4)][ks(6)][64][8] + pad slots + Y1 pads
  {
    const int cb = 16 * w + q * 4;
    const float4 b3v = *reinterpret_cast<const float4*>(b3 + cb);
    const int gC = (cb >> 3) & 3, idx0 = cb & 7, ksb = cb >> 5;  // ksb = w>>1
#pragma unroll
    for (int ntp = 0; ntp < 4; ++ntp) {
      const int pp = ntp * 16 + cl, hd = pp >> 5, pos = pp & 31;
      const unsigned u0 = pk2(acc3[ntp][0] + b3v.x, acc3[ntp][1] + b3v.y);
      const unsigned u1 = pk2(acc3[ntp][2] + b3v.z, acc3[ntp][3] + b3v.w);
      uint2 uu; uu.x = u0; uu.y = u1;
#pragma unroll
      for (int tau = 0; tau < 3; ++tau) {
        const int pt = pos + 1 - tau;
        if ((unsigned)pt < 32u) {
          const int ppt = hd * 32 + pt;
          const int ks = 2 * tau + ksb;
          *reinterpret_cast<uint2*>(
              sX2u + (((size_t)(ppt >> 4) * 6 + ks) * 64 + (ppt & 15) + 16 * gC) * 8 +
              idx0) = uu;
        }
      }
    }
    if (t < 32) {  // pad slots: (tau=0, pos=0) and (tau=2, pos=31) per head
      const int hd = t >> 4, grp = (t >> 3) & 1;
      const int ksz = (grp ? 4 : 0) + ((t >> 2) & 1), kg = t & 3;
      const int ntpz = 2 * hd + grp, lnz = (grp ? 15 : 0) + 16 * kg;
      uint4 z; z.x = z.y = z.z = z.w = 0;
      *reinterpret_cast<uint4*>(&sFr[(size_t)(ntpz * 6 + ksz) * 64 + lnz]) = z;
    }
  }
  __syncthreads();

  // conv1' MFMA: Y1^T[o][p']; wave w -> o-tile w; then Y1 bf16 + pads
  f32x4 accc[4] = {};
#pragma unroll
  for (int ks = 0; ks < 6; ++ks) {
    const s8v a = c1F[(size_t)(w * 6 + ks) * 64 + lane];
#pragma unroll
    for (int ntp = 0; ntp < 4; ++ntp)
      accc[ntp] = mfma16(a, sFr[(size_t)(ntp * 6 + ks) * 64 + lane], accc[ntp]);
  }
  {
    const int o = t >> 2, czi = t & 3;
    const int colz = (czi == 0) ? 0 : (czi == 1) ? 33 : (czi == 2) ? 34 : 67;
    sY1b[o * 68 + colz] = 0;
  }
  {
    const int ob = 16 * w + q * 4;
    const float4 cbv = *reinterpret_cast<const float4*>(c1b + ob);
#pragma unroll
    for (int ntp = 0; ntp < 4; ++ntp) {
      const int pp = ntp * 16 + cl, hd = pp >> 5, pos = pp & 31;
      const int col = hd * 34 + 1 + pos;
      sY1b[(ob + 0) * 68 + col] = f2b(accc[ntp][0] + cbv.x);
      sY1b[(ob + 1) * 68 + col] = f2b(accc[ntp][1] + cbv.y);
      sY1b[(ob + 2) * 68 + col] = f2b(accc[ntp][2] + cbv.z);
      sY1b[(ob + 3) * 68 + col] = f2b(accc[ntp][3] + cbv.w);
    }
  }
  __syncthreads();

  // conv2 (64ch*3tap -> 2) on VALU, K split 2 ways + shuffle reduce, scatter
  {
    const int kq = t & 1, c2 = (t >> 1) & 1, pp = t >> 2;
    const int hd = pp >> 5, pos = pp & 31, col = hd * 34 + 1 + pos;
    float a2 = 0.f;
    const float* wpc = c2w + (size_t)(c2 * 64 + kq * 32) * 3;
    const unsigned short* yb = sY1b + (size_t)(kq * 32) * 68 + col;
#pragma unroll
    for (int o = 0; o < 32; ++o) {
      a2 += b2f(yb[o * 68 - 1]) * wpc[o * 3 + 0] +
            b2f(yb[o * 68]) * wpc[o * 3 + 1] +
            b2f(yb[o * 68 + 1]) * wpc[o * 3 + 2];
    }
    a2 += __shfl_xor(a2, 1, 64);
    if (kq == 0) {
      const int hR_ = hd ? hB_ : hA_;
      const int hidR = hd ? hidB : hidA;
      const int sR = hidR >> 5, offR = hidR & 31;
      const int rel = offR - pos;
      const bool ok = (c2 == 0) ? (rel >= 0) : (rel <= 0);
      out[(size_t)hR_ * 8192 + (size_t)(sR * 32 + pos) * 2 + c2] =
          ok ? (a2 + c2b[c2]) : NEG_SENT;
    }
  }
}

extern "C" void kernel_launch(void* const* d_in, const int* in_sizes, int n_in,
                              void* d_out, int out_size, void* d_ws,
                              size_t ws_size, hipStream_t stream) {
  const float* words = (const float*)d_in[1];
  const int* heads = (const int*)d_in[2];
  const float* emb = (const float*)d_in[3];
  const float* w1 = (const float*)d_in[4];
  const float* b1 = (const float*)d_in[5];
  const float* w2 = (const float*)d_in[6];
  const float* b2 = (const float*)d_in[7];
  const float* w3 = (const float*)d_in[8];
  const float* b3 = (const float*)d_in[9];
  const float* c1w = (const float*)d_in[10];
  const float* c1b = (const float*)d_in[11];
  const float* c2w = (const float*)d_in[12];
  const float* c2b = (const float*)d_in[13];
  float* out = (float*)d_out;

  char* ws = (char*)d_ws;
  unsigned short* embCb = (unsigned short*)ws;      ws += 128 * 1024 * 2;
  unsigned short* AWb = (unsigned short*)ws;        ws += 4096 * 2048 * 2;
  unsigned short* wordsB = (unsigned short*)ws;     ws += 4096 * 768 * 2;
  s8v* w1F = (s8v*)ws;                              ws += 196608 * 16;
  s8v* w2F = (s8v*)ws;                              ws += 32768 * 16;
  s8v* w3F = (s8v*)ws;                              ws += 2048 * 16;
  s8v* c1F = (s8v*)ws;                              ws += 1536 * 16;
  int* ord = (int*)ws;                              ws += 2048 * 4;

  k_prep0<<<2575, 256, 0, stream>>>(words, w1, b1, emb, w2, w3, c1w, heads,
                                    wordsB, w1F, w2F, w3F, c1F, embCb, ord);
  k_mid<<<512, 256, 0, stream>>>(wordsB, w1F, AWb);
  k_fused<<<1024, 256, 0, stream>>>(heads, ord, AWb, embCb, w2F, b2, w3F, b3,
                                    c1F, c1b, c2w, c2b, out);
}

// Round 10
// 218.358 us; speedup vs baseline: 1.2008x; 1.1393x over previous
//
#include <hip/hip_runtime.h>
#include <cstddef>
#include <cstdint>

#define NEG_SENT (-1.0e30f)

// =====================================================================
//  W=4096, H=2048, D=768, HID=1024, E=64, CC=64, K=3, SENT_LEN=32, MD=128
//  sent_id[w]=w>>5 -> packed cols s*32+p all valid; eid=off-p+63 in [32,94]
//
//  R10: consolidation. k_fused = R5's measured-best kernel (99us) with
//  sentence-bucketed head pairs (ord) -- paired heads share a sentence, so
//  staged AWb word rows / embC rows are read twice from the same lines.
//  prep0/k_mid = R9's measured-best non-fused path.
// =====================================================================

typedef short s8v __attribute__((ext_vector_type(8)));
typedef float f32x4 __attribute__((ext_vector_type(4)));

static __device__ __forceinline__ f32x4 mfma16(s8v a, s8v b, f32x4 c) {
  return __builtin_amdgcn_mfma_f32_16x16x32_bf16(a, b, c, 0, 0, 0);
}
static __device__ __forceinline__ unsigned short f2b(float f) {
  union { float f; unsigned u; } v{f};
  unsigned r = v.u + 0x7FFF + ((v.u >> 16) & 1);
  return (unsigned short)(r >> 16);
}
static __device__ __forceinline__ float b2f(unsigned short u) {
  union { unsigned u; float f; } v{((unsigned)u) << 16};
  return v.f;
}
static __device__ __forceinline__ unsigned pk2(float a, float b) {
#if defined(__gfx950__) && __has_builtin(__builtin_amdgcn_cvt_pk_bf16_f32)
  typedef __bf16 b2t __attribute__((ext_vector_type(2)));
  b2t r = __builtin_amdgcn_cvt_pk_bf16_f32(a, b);
  return __builtin_bit_cast(unsigned, r);
#else
  return (unsigned)f2b(a) | ((unsigned)f2b(b) << 16);
#endif
}
static __device__ __forceinline__ float blo(unsigned u) {
  union { unsigned u; float f; } v{u << 16}; return v.f;
}
static __device__ __forceinline__ float bhi(unsigned u) {
  union { unsigned u; float f; } v{u & 0xffff0000u}; return v.f;
}

// ---------- prep0: wordsB (0..1535) | w1F (1536..2303) | w2F (2304..2431)
//   | w3F (2432..2439) | c1F (2440..2445) | embC (2446..2573) | sort (2574)
__global__ __launch_bounds__(256) void k_prep0(
    const float* __restrict__ words, const float* __restrict__ w1,
    const float* __restrict__ b1, const float* __restrict__ emb,
    const float* __restrict__ w2, const float* __restrict__ w3,
    const float* __restrict__ c1w, const int* __restrict__ heads,
    unsigned short* __restrict__ wordsB, s8v* __restrict__ w1F,
    s8v* __restrict__ w2F, s8v* __restrict__ w3F, s8v* __restrict__ c1F,
    unsigned short* __restrict__ embCb, int* __restrict__ ord) {
  const int bx = blockIdx.x, t = threadIdx.x;
  __shared__ float se[64];
  __shared__ int hist[128], base_[128];
  if (bx < 1536) {  // words fp32 -> bf16 row-major
    const size_t o = (size_t)(bx * 256 + t) * 8;
    const float4 v0 = *reinterpret_cast<const float4*>(words + o);
    const float4 v1 = *reinterpret_cast<const float4*>(words + o + 4);
    uint4 r;
    r.x = pk2(v0.x, v0.y); r.y = pk2(v0.z, v0.w);
    r.z = pk2(v1.x, v1.y); r.w = pk2(v1.z, v1.w);
    *reinterpret_cast<uint4*>(wordsB + o) = r;
  } else if (bx < 2304) {  // w1 -> B-frag (N=2048 combined)
    const int tid = (bx - 1536) * 256 + t;
    const int lane = tid & 63, ks = (tid >> 6) % 24, nt = tid / 1536;
    const int n = nt * 16 + (lane & 15);
    const int kb = ks * 32 + 8 * (lane >> 4);
    const int z = n >> 10, col = n & 1023;
    const float* src = w1 + (size_t)(z * 768 + kb) * 1024 + col;
    s8v p;
#pragma unroll
    for (int j = 0; j < 8; ++j) p[j] = (short)f2b(src[(size_t)j * 1024]);
    w1F[tid] = p;
  } else if (bx < 2432) {  // w2 [1024][256] -> [16 nt][32 ks][64][8]
    const int tid = (bx - 2304) * 256 + t;
    const int lane = tid & 63, ks = (tid >> 6) % 32, nt = tid / 2048;
    const int n = nt * 16 + (lane & 15);
    const int kb = ks * 32 + 8 * (lane >> 4);
    s8v p;
#pragma unroll
    for (int j = 0; j < 8; ++j) p[j] = (short)f2b(w2[(size_t)(kb + j) * 256 + n]);
    w2F[tid] = p;
  } else if (bx < 2440) {  // w3 [256][64] -> [4 nt][8 ks][64][8]
    const int tid = (bx - 2432) * 256 + t;
    const int lane = tid & 63, ks = (tid >> 6) % 8, nt = tid / 512;
    const int n = nt * 16 + (lane & 15);
    const int kb = ks * 32 + 8 * (lane >> 4);
    s8v p;
#pragma unroll
    for (int j = 0; j < 8; ++j) p[j] = (short)f2b(w3[(size_t)(kb + j) * 64 + n]);
    w3F[tid] = p;
  } else if (bx < 2446) {  // c1w [64][64][3] -> [4 nt][6 ks][64][8], k=tap*64+c
    const int tid = (bx - 2440) * 256 + t;
    const int lane = tid & 63, ks = (tid >> 6) % 6, nt = tid / 384;
    const int o = nt * 16 + (lane & 15);
    const int kb = ks * 32 + 8 * (lane >> 4);
    s8v p;
#pragma unroll
    for (int j = 0; j < 8; ++j) {
      const int k = kb + j, tap = k >> 6, c = k & 63;
      p[j] = (short)f2b(c1w[(size_t)(o * 64 + c) * 3 + tap]);
    }
    c1F[tid] = p;
  } else if (bx < 2574) {  // embCb[e] = bf16(emb[e] @ w1[1536:1600,:] + b1)
    const int e = bx - 2446;
    if (t < 64) se[t] = emb[e * 64 + t];
    __syncthreads();
    float4 acc = *reinterpret_cast<const float4*>(b1 + 4 * t);
#pragma unroll 8
    for (int d = 0; d < 64; ++d) {
      const float4 wv =
          *reinterpret_cast<const float4*>(w1 + (size_t)(1536 + d) * 1024 + 4 * t);
      const float a = se[d];
      acc.x += a * wv.x; acc.y += a * wv.y; acc.z += a * wv.z; acc.w += a * wv.w;
    }
    uint2 r; r.x = pk2(acc.x, acc.y); r.y = pk2(acc.z, acc.w);
    *reinterpret_cast<uint2*>(embCb + (size_t)e * 1024 + 4 * t) = r;
  } else {  // counting sort of head indices by sentence -> ord[2048]
    if (t < 128) hist[t] = 0;
    __syncthreads();
    for (int h = t; h < 2048; h += 256) atomicAdd(&hist[(heads[h] >> 5) & 127], 1);
    __syncthreads();
    if (t == 0) {
      int s = 0;
      for (int i = 0; i < 128; ++i) { base_[i] = s; s += hist[i]; }
    }
    __syncthreads();
    for (int h = t; h < 2048; h += 256) {
      const int s = (heads[h] >> 5) & 127;
      const int p = atomicAdd(&base_[s], 1);
      ord[p] = h;
    }
  }
}

// ---------- k_mid: GEMM1 -> AWb[4096][2048] bf16 (512 blocks, bf16 A) ------
__global__ __launch_bounds__(256) void k_mid(
    const unsigned short* __restrict__ wordsB, const s8v* __restrict__ w1F,
    unsigned short* __restrict__ AWb) {
  const int bx = blockIdx.x, t = threadIdx.x;
  __shared__ short As[2][8][2][64][8];   // [buf][mt][ks][lane][idx], 32 KB
  const int lane = t & 63, w = t >> 6;
  const int mq = w & 1, nq = w >> 1;
  const int m0 = (bx >> 4) * 128;
  const int nb = bx & 15;
  const int mA = t >> 1;
  const unsigned short* Ap = wordsB + (size_t)(m0 + mA) * 768 + (t & 1) * 32;
  const s8v* Bp = w1F + (size_t)((nb * 8 + nq * 4) * 24) * 64 + lane;

  f32x4 acc[4][4] = {};
  uint4 va[4];
  s8v bc[4][2], bn[4][2];

#pragma unroll
  for (int u = 0; u < 4; ++u) va[u] = *reinterpret_cast<const uint4*>(Ap + 8 * u);
#pragma unroll
  for (int i = 0; i < 4; ++i)
#pragma unroll
    for (int ks = 0; ks < 2; ++ks) bc[i][ks] = Bp[(size_t)(i * 24 + ks) * 64];
#pragma unroll
  for (int u = 0; u < 4; ++u)
    *reinterpret_cast<uint4*>(&As[0][mA >> 4][t & 1][(mA & 15) + 16 * u][0]) = va[u];
  __syncthreads();

#pragma unroll
  for (int it = 0; it < 12; ++it) {
    const int buf = it & 1;
    if (it < 11) {
#pragma unroll
      for (int u = 0; u < 4; ++u)
        va[u] = *reinterpret_cast<const uint4*>(Ap + (it + 1) * 64 + 8 * u);
#pragma unroll
      for (int i = 0; i < 4; ++i)
#pragma unroll
        for (int ks = 0; ks < 2; ++ks)
          bn[i][ks] = Bp[(size_t)(i * 24 + (it + 1) * 2 + ks) * 64];
    }
#pragma unroll
    for (int ks = 0; ks < 2; ++ks) {
      s8v a[4];
#pragma unroll
      for (int i = 0; i < 4; ++i)
        a[i] = *reinterpret_cast<const s8v*>(&As[buf][mq * 4 + i][ks][lane][0]);
#pragma unroll
      for (int i = 0; i < 4; ++i)
#pragma unroll
        for (int j = 0; j < 4; ++j)
          acc[i][j] = mfma16(a[i], bc[j][ks], acc[i][j]);
    }
    if (it < 11) {
#pragma unroll
      for (int u = 0; u < 4; ++u)
        *reinterpret_cast<uint4*>(
            &As[buf ^ 1][mA >> 4][t & 1][(mA & 15) + 16 * u][0]) = va[u];
#pragma unroll
      for (int i = 0; i < 4; ++i)
#pragma unroll
        for (int ks = 0; ks < 2; ++ks) bc[i][ks] = bn[i][ks];
    }
    __syncthreads();
  }

  const int rl = (lane >> 4) * 4, cl2 = lane & 15;
#pragma unroll
  for (int i = 0; i < 4; ++i)
#pragma unroll
    for (int j = 0; j < 4; ++j) {
      const int n = nq * 64 + j * 16 + cl2;
#pragma unroll
      for (int r = 0; r < 4; ++r) {
        const int m = m0 + mq * 64 + i * 16 + rl + r;
        AWb[(size_t)m * 2048 + nb * 128 + n] = f2b(acc[i][j][r]);
      }
    }
}

// ---------- fused per-2-head block (R5 structure + bucketed pairs) ----------
__global__ __launch_bounds__(256, 3) void k_fused(
    const int* __restrict__ heads, const int* __restrict__ ord,
    const unsigned short* __restrict__ AWb,
    const unsigned short* __restrict__ embCb, const s8v* __restrict__ w2F,
    const float* __restrict__ b2, const s8v* __restrict__ w3F,
    const float* __restrict__ b3, const s8v* __restrict__ c1F,
    const float* __restrict__ c1b, const float* __restrict__ c2w,
    const float* __restrict__ c2b, float* __restrict__ out) {
  const int t = threadIdx.x, lane = t & 63, w = t >> 6;
  const int q = lane >> 4, cl = lane & 15;
  const int hA_ = ord[blockIdx.x * 2], hB_ = ord[blockIdx.x * 2 + 1];
  const int hidA = heads[hA_], hidB = heads[hB_];
  const int sA_ = hidA >> 5;
  const int sB_ = hidB >> 5;

  __shared__ unsigned short sHead[2][1024];          // bf16, 4 KB
  __shared__ __align__(16) char rgn[2 * 4 * 4 * 64 * 16];  // 32 KB dbuf/tail
  s8v* sB1 = reinterpret_cast<s8v*>(rgn);
  s8v (*sX2f)[8][64] = reinterpret_cast<s8v(*)[8][64]>(rgn);
  s8v (*sCv)[6][64] = reinterpret_cast<s8v(*)[6][64]>(rgn);
  float* sY1 = reinterpret_cast<float*>(rgn);
  ushort* sX2u = reinterpret_cast<ushort*>(rgn);

  // sentinel fill of both heads' output rows
  {
    float4 m4; m4.x = m4.y = m4.z = m4.w = NEG_SENT;
    float4* o0 = reinterpret_cast<float4*>(out + (size_t)hA_ * 8192);
    float4* o1 = reinterpret_cast<float4*>(out + (size_t)hB_ * 8192);
#pragma unroll
    for (int i = 0; i < 8; ++i) {
      const int fi = t + (i << 8);
      if ((fi >> 4) != sA_) o0[fi] = m4;
      if ((fi >> 4) != sB_) o1[fi] = m4;
    }
  }

  // head rows: AWb[hid][0:1024] bf16 -> LDS (raw)
  {
    const uint2 ha = *reinterpret_cast<const uint2*>(AWb + (size_t)hidA * 2048 + 4 * t);
    const uint2 hb = *reinterpret_cast<const uint2*>(AWb + (size_t)hidB * 2048 + 4 * t);
    *reinterpret_cast<uint2*>(&sHead[0][4 * t]) = ha;
    *reinterpret_cast<uint2*>(&sHead[1][4 * t]) = hb;
  }

  // staging coords: p' = w*16+cl (row), k-quarter q (32 k per chunk-quarter)
  const int pprime = w * 16 + cl;
  const int headS = w >> 1;                // uniform per wave
  const int posS = pprime & 31;
  const int hidS = headS ? hidB : hidA;
  const int offS = hidS & 31;
  const int eidp = offS - posS + 63;       // [32,94]
  const unsigned short* wbase =
      AWb + (size_t)((hidS >> 5) * 32 + posS) * 2048 + 1024 + q * 32;
  const unsigned short* ebase = embCb + (size_t)eidp * 1024 + q * 32;
  const int hbase = headS * 1024 + q * 32;

  uint4 pw[4], pe[4];
#pragma unroll
  for (int g = 0; g < 4; ++g) {
    pw[g] = *reinterpret_cast<const uint4*>(wbase + 8 * g);
    pe[g] = *reinterpret_cast<const uint4*>(ebase + 8 * g);
  }
  __syncthreads();  // sHead visible

  f32x4 acc[4][4] = {};  // [i: n2-tile][ntp: p'-tile]

  // stage chunk0 into buf0
#pragma unroll
  for (int g = 0; g < 4; ++g) {
    const uint4 hv = *reinterpret_cast<const uint4*>(&sHead[0][0] + hbase + 8 * g);
    uint4 r;
    r.x = pk2(fmaxf(blo(pw[g].x) + blo(pe[g].x) + blo(hv.x), 0.f),
              fmaxf(bhi(pw[g].x) + bhi(pe[g].x) + bhi(hv.x), 0.f));
    r.y = pk2(fmaxf(blo(pw[g].y) + blo(pe[g].y) + blo(hv.y), 0.f),
              fmaxf(bhi(pw[g].y) + bhi(pe[g].y) + bhi(hv.y), 0.f));
    r.z = pk2(fmaxf(blo(pw[g].z) + blo(pe[g].z) + blo(hv.z), 0.f),
              fmaxf(bhi(pw[g].z) + bhi(pe[g].z) + bhi(hv.z), 0.f));
    r.w = pk2(fmaxf(blo(pw[g].w) + blo(pe[g].w) + blo(hv.w), 0.f),
              fmaxf(bhi(pw[g].w) + bhi(pe[g].w) + bhi(hv.w), 0.f));
    *reinterpret_cast<uint4*>(&sB1[((0 * 4 + w) * 4 + q) * 64 + cl + 16 * g]) = r;
  }
  __syncthreads();  // buf0 visible

#pragma unroll
  for (int jc = 0; jc < 8; ++jc) {
    const int buf = jc & 1, nbuf = buf ^ 1;
    if (jc < 7) {  // prefetch chunk jc+1 (overlaps MFMA below)
      const int j1 = (jc + 1) * 128;
#pragma unroll
      for (int g = 0; g < 4; ++g) {
        pw[g] = *reinterpret_cast<const uint4*>(wbase + j1 + 8 * g);
        pe[g] = *reinterpret_cast<const uint4*>(ebase + j1 + 8 * g);
      }
    }
    // GEMM2' MFMA on buf
    const int ksg0 = jc * 4;
#pragma unroll
    for (int ks2 = 0; ks2 < 4; ++ks2) {
      s8v av[4], bv[4];
#pragma unroll
      for (int i = 0; i < 4; ++i)
        av[i] = w2F[(size_t)((w * 4 + i) * 32 + ksg0 + ks2) * 64 + lane];
#pragma unroll
      for (int ntp = 0; ntp < 4; ++ntp)
        bv[ntp] = sB1[((buf * 4 + ntp) * 4 + ks2) * 64 + lane];
#pragma unroll
      for (int i = 0; i < 4; ++i)
#pragma unroll
        for (int ntp = 0; ntp < 4; ++ntp)
          acc[i][ntp] = mfma16(av[i], bv[ntp], acc[i][ntp]);
    }
    if (jc < 7) {  // compute + store chunk jc+1 into nbuf
      const int j1 = (jc + 1) * 128;
#pragma unroll
      for (int g = 0; g < 4; ++g) {
        const uint4 hv =
            *reinterpret_cast<const uint4*>(&sHead[0][0] + hbase + j1 + 8 * g);
        uint4 r;
        r.x = pk2(fmaxf(blo(pw[g].x) + blo(pe[g].x) + blo(hv.x), 0.f),
                  fmaxf(bhi(pw[g].x) + bhi(pe[g].x) + bhi(hv.x), 0.f));
        r.y = pk2(fmaxf(blo(pw[g].y) + blo(pe[g].y) + blo(hv.y), 0.f),
                  fmaxf(bhi(pw[g].y) + bhi(pe[g].y) + bhi(hv.y), 0.f));
        r.z = pk2(fmaxf(blo(pw[g].z) + blo(pe[g].z) + blo(hv.z), 0.f),
                  fmaxf(bhi(pw[g].z) + bhi(pe[g].z) + bhi(hv.z), 0.f));
        r.w = pk2(fmaxf(blo(pw[g].w) + blo(pe[g].w) + blo(hv.w), 0.f),
                  fmaxf(bhi(pw[g].w) + bhi(pe[g].w) + bhi(hv.w), 0.f));
        *reinterpret_cast<uint4*>(
            &sB1[((nbuf * 4 + w) * 4 + q) * 64 + cl + 16 * g]) = r;
      }
    }
    __syncthreads();
  }

  // GEMM2' epilogue: X2^T = relu(acc + b2) -> B-frags for GEMM3'
#pragma unroll
  for (int i = 0; i < 4; ++i) {
    const int n2b = w * 64 + i * 16 + q * 4;
    const float4 bb = *reinterpret_cast<const float4*>(b2 + n2b);
    const int ks3 = n2b >> 5, g3 = (n2b >> 3) & 3, idx0 = n2b & 7;
#pragma unroll
    for (int ntp = 0; ntp < 4; ++ntp) {
      const unsigned u0 = pk2(fmaxf(acc[i][ntp][0] + bb.x, 0.f),
                              fmaxf(acc[i][ntp][1] + bb.y, 0.f));
      const unsigned u1 = pk2(fmaxf(acc[i][ntp][2] + bb.z, 0.f),
                              fmaxf(acc[i][ntp][3] + bb.w, 0.f));
      uint2 uu; uu.x = u0; uu.y = u1;
      *reinterpret_cast<uint2*>(
          sX2u + (((size_t)ntp * 8 + ks3) * 64 + cl + 16 * g3) * 8 + idx0) = uu;
    }
  }
  __syncthreads();

  // GEMM3': X3^T[c][p'] ; wave w -> c-tile w
  f32x4 acc3[4] = {};
#pragma unroll
  for (int ks3 = 0; ks3 < 8; ++ks3) {
    const s8v a = w3F[(size_t)(w * 8 + ks3) * 64 + lane];
#pragma unroll
    for (int ntp = 0; ntp < 4; ++ntp)
      acc3[ntp] = mfma16(a, sX2f[ntp][ks3][lane], acc3[ntp]);
  }
  __syncthreads();

  // zero conv frag region (24 KB)
  {
    uint4 z; z.x = z.y = z.z = z.w = 0;
    uint4* zp = reinterpret_cast<uint4*>(rgn);
#pragma unroll
    for (int i2 = 0; i2 < 6; ++i2) zp[t + 256 * i2] = z;
  }
  __syncthreads();

  // conv1' im2col frag writes
  {
    const int cb = 16 * w + q * 4;
    const float4 b3v = *reinterpret_cast<const float4*>(b3 + cb);
    const int gC = (cb >> 3) & 3, idx0 = cb & 7, ksb = cb >> 5;
#pragma unroll
    for (int ntp = 0; ntp < 4; ++ntp) {
      const int pp = ntp * 16 + cl, hd = pp >> 5, pos = pp & 31;
      const unsigned u0 = pk2(acc3[ntp][0] + b3v.x, acc3[ntp][1] + b3v.y);
      const unsigned u1 = pk2(acc3[ntp][2] + b3v.z, acc3[ntp][3] + b3v.w);
      uint2 uu; uu.x = u0; uu.y = u1;
#pragma unroll
      for (int tau = 0; tau < 3; ++tau) {
        const int pt = pos + 1 - tau;
        if ((unsigned)pt < 32u) {
          const int ppt = hd * 32 + pt;
          const int ks = 2 * tau + ksb;
          *reinterpret_cast<uint2*>(
              sX2u + (((size_t)(ppt >> 4) * 6 + ks) * 64 + (ppt & 15) + 16 * gC) * 8 +
              idx0) = uu;
        }
      }
    }
  }
  __syncthreads();

  // conv1' MFMA: Y1^T[o][p'] ; wave w -> o-tile w
  f32x4 accc[4] = {};
#pragma unroll
  for (int ks = 0; ks < 6; ++ks) {
    const s8v a = c1F[(size_t)(w * 6 + ks) * 64 + lane];
#pragma unroll
    for (int ntp = 0; ntp < 4; ++ntp)
      accc[ntp] = mfma16(a, sCv[ntp][ks][lane], accc[ntp]);
  }
  __syncthreads();

  // Y1^T -> fp32 LDS [64 o][68] with per-head zero pad cols (0,33,34,67)
  {
    const int o = t >> 2, pc = t & 3;
    const int colz = (pc == 0) ? 0 : (pc == 1) ? 33 : (pc == 2) ? 34 : 67;
    sY1[o * 68 + colz] = 0.f;
  }
  {
    const int ob = 16 * w + q * 4;
    const float4 cbv = *reinterpret_cast<const float4*>(c1b + ob);
#pragma unroll
    for (int ntp = 0; ntp < 4; ++ntp) {
      const int pp = ntp * 16 + cl, hd = pp >> 5, pos = pp & 31;
      const int col = hd * 34 + 1 + pos;
      sY1[(ob + 0) * 68 + col] = accc[ntp][0] + cbv.x;
      sY1[(ob + 1) * 68 + col] = accc[ntp][1] + cbv.y;
      sY1[(ob + 2) * 68 + col] = accc[ntp][2] + cbv.z;
      sY1[(ob + 3) * 68 + col] = accc[ntp][3] + cbv.w;
    }
  }
  __syncthreads();

  // conv2 (64ch*3tap -> 2) on VALU, K split 2 ways + shuffle reduce, scatter
  {
    const int kq = t & 1, c2 = (t >> 1) & 1, pp = t >> 2;
    const int hd = pp >> 5, pos = pp & 31, col = hd * 34 + 1 + pos;
    float a2 = 0.f;
    const float* wp = c2w + (size_t)(c2 * 64 + kq * 32) * 3;
    const float* yb = sY1 + (size_t)(kq * 32) * 68 + col;
#pragma unroll
    for (int o = 0; o < 32; ++o) {
      a2 += yb[o * 68 - 1] * wp[o * 3 + 0] + yb[o * 68] * wp[o * 3 + 1] +
            yb[o * 68 + 1] * wp[o * 3 + 2];
    }
    a2 += __shfl_xor(a2, 1, 64);
    if (kq == 0) {
      const int hR_ = hd ? hB_ : hA_;
      const int hidR = hd ? hidB : hidA;
      const int sR = hidR >> 5, offR = hidR & 31;
      const int rel = offR - pos;
      const bool ok = (c2 == 0) ? (rel >= 0) : (rel <= 0);
      out[(size_t)hR_ * 8192 + (size_t)(sR * 32 + pos) * 2 + c2] =
          ok ? (a2 + c2b[c2]) : NEG_SENT;
    }
  }
}

extern "C" void kernel_launch(void* const* d_in, const int* in_sizes, int n_in,
                              void* d_out, int out_size, void* d_ws,
                              size_t ws_size, hipStream_t stream) {
  const float* words = (const float*)d_in[1];
  const int* heads = (const int*)d_in[2];
  const float* emb = (const float*)d_in[3];
  const float* w1 = (const float*)d_in[4];
  const float* b1 = (const float*)d_in[5];
  const float* w2 = (const float*)d_in[6];
  const float* b2 = (const float*)d_in[7];
  const float* w3 = (const float*)d_in[8];
  const float* b3 = (const float*)d_in[9];
  const float* c1w = (const float*)d_in[10];
  const float* c1b = (const float*)d_in[11];
  const float* c2w = (const float*)d_in[12];
  const float* c2b = (const float*)d_in[13];
  float* out = (float*)d_out;

  char* ws = (char*)d_ws;
  unsigned short* embCb = (unsigned short*)ws;      ws += 128 * 1024 * 2;
  unsigned short* AWb = (unsigned short*)ws;        ws += 4096 * 2048 * 2;
  unsigned short* wordsB = (unsigned short*)ws;     ws += 4096 * 768 * 2;
  s8v* w1F = (s8v*)ws;                              ws += 196608 * 16;
  s8v* w2F = (s8v*)ws;                              ws += 32768 * 16;
  s8v* w3F = (s8v*)ws;                              ws += 2048 * 16;
  s8v* c1F = (s8v*)ws;                              ws += 1536 * 16;
  int* ord = (int*)ws;                              ws += 2048 * 4;

  k_prep0<<<2575, 256, 0, stream>>>(words, w1, b1, emb, w2, w3, c1w, heads,
                                    wordsB, w1F, w2F, w3F, c1F, embCb, ord);
  k_mid<<<512, 256, 0, stream>>>(wordsB, w1F, AWb);
  k_fused<<<1024, 256, 0, stream>>>(heads, ord, AWb, embCb, w2F, b2, w3F, b3,
                                    c1F, c1b, c2w, c2b, out);
}